// Round 5
// baseline (395.562 us; speedup 1.0000x reference)
//
#include <hip/hip_runtime.h>
#include <math.h>

#define D_H 128

typedef __attribute__((ext_vector_type(8))) __bf16 bf16x8;
typedef __attribute__((ext_vector_type(4))) float f32x4;

__device__ __forceinline__ void split_bf16(float v, unsigned short& hi, unsigned short& lo) {
  unsigned int u = __float_as_uint(v);
  hi = (unsigned short)(u >> 16);
  float l = v - __uint_as_float(u & 0xffff0000u);
  lo = (unsigned short)(__float_as_uint(l) >> 16);
}

__device__ __forceinline__ void pack_pair(const float* xv, bf16x8& ah, bf16x8& al) {
  union { bf16x8 v; unsigned int u[4]; } H, L;
#pragma unroll
  for (int e = 0; e < 4; ++e) {
    unsigned short h0, l0, h1, l1;
    split_bf16(xv[2 * e], h0, l0);
    split_bf16(xv[2 * e + 1], h1, l1);
    H.u[e] = (unsigned int)h0 | ((unsigned int)h1 << 16);
    L.u[e] = (unsigned int)l0 | ((unsigned int)l1 << 16);
  }
  ah = H.v;
  al = L.v;
}

// ---------------- graph build ----------------

__global__ void k_deg(const int* __restrict__ dstv, int* __restrict__ deg, int E) {
  for (int i = blockIdx.x * blockDim.x + threadIdx.x; i < E; i += gridDim.x * blockDim.x)
    atomicAdd(&deg[dstv[i]], 1);
}

__global__ __launch_bounds__(256) void k_partial(const int* __restrict__ deg,
                                                 int* __restrict__ partials, int N) {
  __shared__ int s[256];
  int t = threadIdx.x;
  int i = blockIdx.x * 256 + t;
  s[t] = (i < N) ? deg[i] : 0;
  __syncthreads();
  for (int off = 128; off > 0; off >>= 1) {
    if (t < off) s[t] += s[t + off];
    __syncthreads();
  }
  if (t == 0) partials[blockIdx.x] = s[0];
}

__global__ __launch_bounds__(256) void k_scanpart(int* __restrict__ partials, int NB,
                                                  int* __restrict__ row_ptr, int N) {
  __shared__ int s[256];
  int t = threadIdx.x;
  int v = (t < NB) ? partials[t] : 0;
  s[t] = v;
  __syncthreads();
  for (int off = 1; off < 256; off <<= 1) {
    int u = (t >= off) ? s[t - off] : 0;
    __syncthreads();
    s[t] += u;
    __syncthreads();
  }
  if (t < NB) partials[t] = s[t] - v;
  if (t == 255) row_ptr[N] = s[255];
}

__global__ __launch_bounds__(256) void k_rowptr(const int* __restrict__ deg,
                                                const int* __restrict__ partials,
                                                int* __restrict__ row_ptr,
                                                int* __restrict__ cnt, int N) {
  __shared__ int s[256];
  int t = threadIdx.x;
  int i = blockIdx.x * 256 + t;
  int v = (i < N) ? deg[i] : 0;
  s[t] = v;
  __syncthreads();
  for (int off = 1; off < 256; off <<= 1) {
    int u = (t >= off) ? s[t - off] : 0;
    __syncthreads();
    s[t] += u;
    __syncthreads();
  }
  if (i < N) {
    int ex = partials[blockIdx.x] + s[t] - v;
    row_ptr[i] = ex;
    cnt[i] = ex;
  }
}

__global__ void k_scatter(const int* __restrict__ srcv, const int* __restrict__ dstv,
                          int* __restrict__ cnt, int* __restrict__ col, int E) {
  for (int i = blockIdx.x * blockDim.x + threadIdx.x; i < E; i += gridDim.x * blockDim.x) {
    int d = dstv[i];
    int pos = atomicAdd(&cnt[d], 1);
    col[pos] = srcv[i];
  }
}

// ---------------- weight split (once) ----------------
// emb: [128][640 shorts] = [320 hi | 320 lo] (K padded 300->320, zeros)
// conv: [128][256 shorts] = [128 hi | 128 lo]

__global__ __launch_bounds__(256) void k_wsplit(
    const float* __restrict__ Wemb, const float* __restrict__ Wl0,
    const float* __restrict__ Wr0, const float* __restrict__ Wl1,
    const float* __restrict__ Wr1, unsigned short* __restrict__ WembP,
    unsigned short* __restrict__ P0l, unsigned short* __restrict__ P0r,
    unsigned short* __restrict__ P1l, unsigned short* __restrict__ P1r) {
  int tid = blockIdx.x * 256 + threadIdx.x;
  const int EMB = 128 * 320;
  if (tid < EMB) {
    int o = tid / 320, k = tid - o * 320;
    float v = (k < 300) ? Wemb[o * 300 + k] : 0.f;
    unsigned short h, l;
    split_bf16(v, h, l);
    WembP[o * 640 + k] = h;
    WembP[o * 640 + 320 + k] = l;
  } else if (tid < EMB + 4 * 16384) {
    int r = tid - EMB;
    int m = r >> 14;
    int i = r & 16383;
    int o = i >> 7, k = i & 127;
    const float* W = (m == 0) ? Wl0 : (m == 1) ? Wr0 : (m == 2) ? Wl1 : Wr1;
    unsigned short* P = (m == 0) ? P0l : (m == 1) ? P0r : (m == 2) ? P1l : P1r;
    unsigned short h, l;
    split_bf16(W[o * 128 + k], h, l);
    P[o * 256 + k] = h;
    P[o * 256 + 128 + k] = l;
  }
}

// ---------------- emb GEMM: P = pair( x @ Wemb^T + b ) ----------------
// no LDS staging, no barriers in main loop. Block = 64 rows, 4 waves = 2wr x 2wc,
// each wave 32 rows x 64 cols (2x4 fragments of 16x16x32). K = 320 (10 steps).

__global__ __launch_bounds__(256, 3) void k_emb(const float* __restrict__ x,
                                                const unsigned short* __restrict__ Wp,
                                                const float* __restrict__ bias,
                                                unsigned short* __restrict__ P, int N) {
  int t = threadIdx.x, lane = t & 63, wave = t >> 6;
  int wr = wave >> 1, wc = wave & 1;
  int row0 = blockIdx.x * 64;
  int fr = lane & 15;
  int fk = (lane >> 4) * 8;
  int fob = (lane >> 4) * 16;
  f32x4 acc[2][4] = {};

  for (int ks = 0; ks < 10; ++ks) {
    bf16x8 ah[2], al[2];
#pragma unroll
    for (int i = 0; i < 2; ++i) {
      int row = row0 + wr * 32 + i * 16 + fr;
      if (row >= N) row = N - 1;
      int c0 = ks * 32 + fk;
      const float* xr = x + (size_t)row * 300 + c0;
      float xv[8];
      if (c0 + 7 < 300) {
        float4 v0 = *(const float4*)xr;
        float4 v1 = *(const float4*)(xr + 4);
        xv[0] = v0.x; xv[1] = v0.y; xv[2] = v0.z; xv[3] = v0.w;
        xv[4] = v1.x; xv[5] = v1.y; xv[6] = v1.z; xv[7] = v1.w;
      } else {
#pragma unroll
        for (int e = 0; e < 8; ++e) xv[e] = (c0 + e < 300) ? xr[e] : 0.f;
      }
      pack_pair(xv, ah[i], al[i]);
    }
#pragma unroll
    for (int j = 0; j < 4; ++j) {
      const char* wb = (const char*)Wp + (size_t)(wc * 64 + j * 16 + fr) * 1280 + ks * 64 + fob;
      bf16x8 bh = *(const bf16x8*)wb;
      bf16x8 bl = *(const bf16x8*)(wb + 640);
#pragma unroll
      for (int i = 0; i < 2; ++i) {
        acc[i][j] = __builtin_amdgcn_mfma_f32_16x16x32_bf16(ah[i], bh, acc[i][j], 0, 0, 0);
        acc[i][j] = __builtin_amdgcn_mfma_f32_16x16x32_bf16(ah[i], bl, acc[i][j], 0, 0, 0);
        acc[i][j] = __builtin_amdgcn_mfma_f32_16x16x32_bf16(al[i], bh, acc[i][j], 0, 0, 0);
      }
    }
  }

  // epilogue: acc -> LDS (f32, stride 133 = conflict-free) -> pair stores (16B)
  __shared__ float T[64 * 133];
  int cr0 = (lane >> 4) * 4;
#pragma unroll
  for (int j = 0; j < 4; ++j) {
    int colj = wc * 64 + j * 16 + fr;
    float b = bias[colj];
#pragma unroll
    for (int i = 0; i < 2; ++i) {
      int rl = wr * 32 + i * 16 + cr0;
#pragma unroll
      for (int rg = 0; rg < 4; ++rg) T[(rl + rg) * 133 + colj] = acc[i][j][rg] + b;
    }
  }
  __syncthreads();
  int r = t & 63, q = t >> 6;
  float vals[32];
#pragma unroll
  for (int c = 0; c < 32; ++c) vals[c] = T[r * 133 + q * 32 + c];
  unsigned int hu[16], lu[16];
#pragma unroll
  for (int e = 0; e < 16; ++e) {
    unsigned short h0, l0, h1, l1;
    split_bf16(vals[2 * e], h0, l0);
    split_bf16(vals[2 * e + 1], h1, l1);
    hu[e] = (unsigned int)h0 | ((unsigned int)h1 << 16);
    lu[e] = (unsigned int)l0 | ((unsigned int)l1 << 16);
  }
  char* rowp = (char*)P + (size_t)(row0 + r) * 512;
  uint4* dh = (uint4*)(rowp + q * 64);
  uint4* dl = (uint4*)(rowp + 256 + q * 64);
#pragma unroll
  for (int k = 0; k < 4; ++k) {
    dh[k] = make_uint4(hu[4 * k], hu[4 * k + 1], hu[4 * k + 2], hu[4 * k + 3]);
    dl[k] = make_uint4(lu[4 * k], lu[4 * k + 1], lu[4 * k + 2], lu[4 * k + 3]);
  }
}

// ---------------- conv GEMM: U = A@Wl^T, V = A@Wr^T (fp32 out) ----------------
// A pair [rows][256 shorts]. Block = 64 rows, 4 waves = (out, wc), each wave
// 64 rows x 64 cols of one output. No LDS, no barriers. K=128 (4 steps).

__global__ __launch_bounds__(256, 3) void k_conv(const unsigned short* __restrict__ Ap,
                                                 const unsigned short* __restrict__ Wl,
                                                 const unsigned short* __restrict__ Wr,
                                                 float* __restrict__ U,
                                                 float* __restrict__ V) {
  int t = threadIdx.x, lane = t & 63, wave = t >> 6;
  int om = wave >> 1, wc = wave & 1;
  const unsigned short* W = om ? Wr : Wl;
  float* OUT = om ? V : U;
  int row0 = blockIdx.x * 64;
  int fr = lane & 15;
  int fob = (lane >> 4) * 16;
  f32x4 acc[4][4] = {};

  for (int ks = 0; ks < 4; ++ks) {
    bf16x8 ah[4], al[4];
#pragma unroll
    for (int i = 0; i < 4; ++i) {
      const char* ab = (const char*)Ap + (size_t)(row0 + i * 16 + fr) * 512 + ks * 64 + fob;
      ah[i] = *(const bf16x8*)ab;
      al[i] = *(const bf16x8*)(ab + 256);
    }
#pragma unroll
    for (int j = 0; j < 4; ++j) {
      const char* wb = (const char*)W + (size_t)(wc * 64 + j * 16 + fr) * 512 + ks * 64 + fob;
      bf16x8 bh = *(const bf16x8*)wb;
      bf16x8 bl = *(const bf16x8*)(wb + 256);
#pragma unroll
      for (int i = 0; i < 4; ++i) {
        acc[i][j] = __builtin_amdgcn_mfma_f32_16x16x32_bf16(ah[i], bh, acc[i][j], 0, 0, 0);
        acc[i][j] = __builtin_amdgcn_mfma_f32_16x16x32_bf16(ah[i], bl, acc[i][j], 0, 0, 0);
        acc[i][j] = __builtin_amdgcn_mfma_f32_16x16x32_bf16(al[i], bh, acc[i][j], 0, 0, 0);
      }
    }
  }

  int cr0 = (lane >> 4) * 4;
  int cc = lane & 15;
#pragma unroll
  for (int i = 0; i < 4; ++i)
#pragma unroll
    for (int j = 0; j < 4; ++j)
#pragma unroll
      for (int rg = 0; rg < 4; ++rg)
        OUT[(size_t)(row0 + i * 16 + cr0 + rg) * D_H + wc * 64 + j * 16 + cc] = acc[i][j][rg];
}

// ---------------- fused aggregate + epilogue ----------------
// h' = relu( mean-gather(U) + V + bias ); OUTP=1 -> pair out, OUTP=0 -> fp32
// in-place into V. One wave per node, float2 per lane.

template <int OUTP>
__global__ __launch_bounds__(256) void k_aggfin(const float* __restrict__ U,
                                                float* __restrict__ V,
                                                const float* __restrict__ bias,
                                                const int* __restrict__ row_ptr,
                                                const int* __restrict__ col,
                                                unsigned short* __restrict__ Hp, int N) {
  int wid = blockIdx.x * 4 + (threadIdx.x >> 6);
  if (wid >= N) return;
  int lane = threadIdx.x & 63;
  const float2* uv = (const float2*)U;
  int e0 = row_ptr[wid], e1 = row_ptr[wid + 1];
  float ax = 0.f, ay = 0.f;
  int e = e0;
  for (; e + 4 <= e1; e += 4) {
    int s0 = col[e], s1 = col[e + 1], s2 = col[e + 2], s3 = col[e + 3];
    float2 v0 = uv[(size_t)s0 * 64 + lane];
    float2 v1 = uv[(size_t)s1 * 64 + lane];
    float2 v2 = uv[(size_t)s2 * 64 + lane];
    float2 v3 = uv[(size_t)s3 * 64 + lane];
    ax += v0.x + v1.x + v2.x + v3.x;
    ay += v0.y + v1.y + v2.y + v3.y;
  }
  for (; e < e1; ++e) {
    float2 v = uv[(size_t)col[e] * 64 + lane];
    ax += v.x;
    ay += v.y;
  }
  float inv = 1.f / fmaxf((float)(e1 - e0), 1.f);
  float2 vv = ((const float2*)V)[(size_t)wid * 64 + lane];
  float2 bb = ((const float2*)bias)[lane];
  float ox = fmaxf(ax * inv + vv.x + bb.x, 0.f);
  float oy = fmaxf(ay * inv + vv.y + bb.y, 0.f);
  if (OUTP) {
    unsigned short hx, lx, hy, ly;
    split_bf16(ox, hx, lx);
    split_bf16(oy, hy, ly);
    ((unsigned int*)((char*)Hp + (size_t)wid * 512))[lane] =
        (unsigned int)hx | ((unsigned int)hy << 16);
    ((unsigned int*)((char*)Hp + (size_t)wid * 512 + 256))[lane] =
        (unsigned int)lx | ((unsigned int)ly << 16);
  } else {
    ((float2*)V)[(size_t)wid * 64 + lane] = make_float2(ox, oy);
  }
}

// ---------------- attention readout ----------------

__global__ __launch_bounds__(256) void k_score(const float* __restrict__ h,
                                               const float* __restrict__ watt,
                                               const float* __restrict__ batt,
                                               float* __restrict__ scores,
                                               float* __restrict__ partmax, int N) {
  __shared__ float smax[16];
  int t = threadIdx.x;
  int grp = t >> 4, l = t & 15;
  int node = blockIdx.x * 16 + grp;
  float sc = -3.0e38f;
  if (node < N) {
    const float2* hv = (const float2*)(h + (size_t)node * D_H);
    const float2* wv = (const float2*)watt;
    float acc = 0.f;
#pragma unroll
    for (int i = 0; i < 4; ++i) {
      float2 a = hv[i * 16 + l];
      float2 w = wv[i * 16 + l];
      acc = fmaf(a.x, w.x, acc);
      acc = fmaf(a.y, w.y, acc);
    }
#pragma unroll
    for (int off = 8; off > 0; off >>= 1) acc += __shfl_down(acc, off, 16);
    if (l == 0) {
      sc = acc + batt[0];
      scores[node] = sc;
    }
  }
  if (l == 0) smax[grp] = sc;
  __syncthreads();
  if (t == 0) {
    float m = smax[0];
    for (int i = 1; i < 16; ++i) m = fmaxf(m, smax[i]);
    partmax[blockIdx.x] = m;
  }
}

__global__ __launch_bounds__(256) void k_redmax(const float* __restrict__ partmax, int PB,
                                                float* __restrict__ red) {
  __shared__ float sm[256];
  int t = threadIdx.x;
  float m = -3.0e38f;
  for (int i = t; i < PB; i += 256) m = fmaxf(m, partmax[i]);
  sm[t] = m;
  __syncthreads();
  for (int off = 128; off > 0; off >>= 1) {
    if (t < off) sm[t] = fmaxf(sm[t], sm[t + off]);
    __syncthreads();
  }
  if (t == 0) {
    red[0] = sm[0];
    red[1] = 0.f;
  }
  for (int i = t; i < 1024; i += 256) red[2 + i] = 0.f;
}

__global__ __launch_bounds__(256) void k_pool(const float* __restrict__ h,
                                              const float* __restrict__ scores,
                                              const int* __restrict__ batch,
                                              float* __restrict__ red, int N, int nblocks) {
  __shared__ float pl[4][1024];
  __shared__ float zp[4];
  int t = threadIdx.x;
  int w = t >> 6, lane = t & 63;
  for (int i = lane; i < 1024; i += 64) pl[w][i] = 0.f;
  float M = red[0];
  float zacc = 0.f;
  const float2* hv = (const float2*)h;
  int stride = nblocks * 4;
  for (int node = blockIdx.x * 4 + w; node < N; node += stride) {
    float wgt = __expf(scores[node] - M);
    int b = batch[node];
    float2 v = hv[(size_t)node * 64 + lane];
    pl[w][b * 128 + lane * 2] += v.x * wgt;
    pl[w][b * 128 + lane * 2 + 1] += v.y * wgt;
    zacc += wgt;
  }
  if (lane == 0) zp[w] = zacc;
  __syncthreads();
  for (int i = t; i < 1024; i += 256) {
    float s = pl[0][i] + pl[1][i] + pl[2][i] + pl[3][i];
    atomicAdd(&red[2 + i], s);
  }
  if (t == 0) atomicAdd(&red[1], zp[0] + zp[1] + zp[2] + zp[3]);
}

__global__ __launch_bounds__(512) void k_out(const float* __restrict__ red,
                                             const float* __restrict__ Wout,
                                             const float* __restrict__ bout,
                                             float* __restrict__ out) {
  int t = threadIdx.x;
  int gIdx = t >> 6, o = t & 63;
  float invZ = 1.f / red[1];
  const float* p = red + 2 + gIdx * 128;
  const float* wr = Wout + (size_t)o * 128;
  float acc = 0.f;
  for (int k = 0; k < 128; ++k) acc = fmaf(p[k], wr[k], acc);
  out[gIdx * 64 + o] = acc * invZ + bout[o];
}

// ---------------- launcher ----------------

extern "C" void kernel_launch(void* const* d_in, const int* in_sizes, int n_in,
                              void* d_out, int out_size, void* d_ws, size_t ws_size,
                              hipStream_t stream) {
  const float* x     = (const float*)d_in[0];
  const int*   ei    = (const int*)d_in[1];
  const int*   batch = (const int*)d_in[2];
  const float* W_emb = (const float*)d_in[3];
  const float* b_emb = (const float*)d_in[4];
  const float* Wl0   = (const float*)d_in[5];
  const float* bl0   = (const float*)d_in[6];
  const float* Wr0   = (const float*)d_in[7];
  const float* Wl1   = (const float*)d_in[8];
  const float* bl1   = (const float*)d_in[9];
  const float* Wr1   = (const float*)d_in[10];
  const float* W_att = (const float*)d_in[11];
  const float* b_att = (const float*)d_in[12];
  const float* W_out = (const float*)d_in[13];
  const float* b_out = (const float*)d_in[14];
  float* out = (float*)d_out;

  const int DIN = 300;
  int N = in_sizes[0] / DIN;
  int E = in_sizes[1] / 2;
  int Npad = (N + 63) & ~63;

  char* wsp = (char*)d_ws;
  size_t off = 0;
  auto carve = [&](size_t bytes) -> void* {
    void* p = wsp + off;
    off += (bytes + 255) & ~(size_t)255;
    return p;
  };
  unsigned short* P = (unsigned short*)carve((size_t)Npad * 512);  // h pairs
  float*          U = (float*)carve((size_t)Npad * 512);           // A@Wl fp32
  float*          V = (float*)carve((size_t)Npad * 512);           // A@Wr fp32 / h2
  unsigned short* WembP = (unsigned short*)carve((size_t)128 * 640 * 2);
  unsigned short* WP0l  = (unsigned short*)carve((size_t)128 * 256 * 2);
  unsigned short* WP0r  = (unsigned short*)carve((size_t)128 * 256 * 2);
  unsigned short* WP1l  = (unsigned short*)carve((size_t)128 * 256 * 2);
  unsigned short* WP1r  = (unsigned short*)carve((size_t)128 * 256 * 2);
  int*   colA    = (int*)carve((size_t)E * 4);
  int*   row_ptr = (int*)carve((size_t)(N + 1) * 4);
  int*   deg     = (int*)carve((size_t)N * 4);
  int*   cnt     = (int*)carve((size_t)N * 4);
  float* scores  = (float*)carve((size_t)N * 4);
  int scoreBlocks = (N + 15) / 16;
  float* partmax = (float*)carve((size_t)scoreBlocks * 4);
  float* red     = (float*)carve((size_t)(2 + 1024) * 4);
  int scanBlocks = (N + 255) / 256;
  int*   partials = (int*)carve((size_t)scanBlocks * 4);

  const int* srcv = ei;
  const int* dstv = ei + E;

  hipMemsetAsync(deg, 0, (size_t)N * 4, stream);
  k_deg<<<1024, 256, 0, stream>>>(dstv, deg, E);
  k_wsplit<<<(128 * 320 + 4 * 16384 + 255) / 256, 256, 0, stream>>>(
      W_emb, Wl0, Wr0, Wl1, Wr1, WembP, WP0l, WP0r, WP1l, WP1r);
  k_partial<<<scanBlocks, 256, 0, stream>>>(deg, partials, N);
  k_scanpart<<<1, 256, 0, stream>>>(partials, scanBlocks, row_ptr, N);
  k_rowptr<<<scanBlocks, 256, 0, stream>>>(deg, partials, row_ptr, cnt, N);
  k_scatter<<<1024, 256, 0, stream>>>(srcv, dstv, cnt, colA, E);

  int gblocks = Npad / 64;
  // h0 pair
  k_emb<<<gblocks, 256, 0, stream>>>(x, WembP, b_emb, P, N);
  // conv0: U = h0@Wl0^T, V = h0@Wr0^T ; then h1 = relu(mean(U) + V + bl0) -> pair P
  k_conv<<<gblocks, 256, 0, stream>>>(P, WP0l, WP0r, U, V);
  k_aggfin<1><<<(N + 3) / 4, 256, 0, stream>>>(U, V, bl0, row_ptr, colA, P, N);
  // conv1: same; h2 fp32 in-place into V
  k_conv<<<gblocks, 256, 0, stream>>>(P, WP1l, WP1r, U, V);
  k_aggfin<0><<<(N + 3) / 4, 256, 0, stream>>>(U, V, bl1, row_ptr, colA, nullptr, N);

  const float* h2 = (const float*)V;
  k_score<<<scoreBlocks, 256, 0, stream>>>(h2, W_att, b_att, scores, partmax, N);
  k_redmax<<<1, 256, 0, stream>>>(partmax, scoreBlocks, red);
  k_pool<<<256, 256, 0, stream>>>(h2, scores, batch, red, N, 256);
  k_out<<<1, 512, 0, stream>>>(red, W_out, b_out, out);
}